// Round 9
// baseline (201.261 us; speedup 1.0000x reference)
//
#include <hip/hip_runtime.h>

#define NB 256
#define NM 128
#define ND 64
#define NH 8

typedef float f32x4 __attribute__((ext_vector_type(4)));
typedef short bf16x8 __attribute__((ext_vector_type(8)));   // 8 bf16 = 4 VGPRs
typedef unsigned short ushort_t;

__device__ __forceinline__ ushort_t f2bf(float f) {   // RNE f32->bf16
    unsigned int x = __float_as_uint(f);
    x += 0x7fffu + ((x >> 16) & 1u);
    return (ushort_t)(x >> 16);
}

// XOR-swizzled LDS indices (T2): col ^= 8*(row&7). Applied on BOTH write and read.
__device__ __forceinline__ int sw64(int row, int col)  { return row * 64  + (col ^ ((row & 7) << 3)); }
__device__ __forceinline__ int sw128(int row, int col) { return row * 128 + (col ^ ((row & 7) << 3)); }

__device__ __forceinline__ f32x4 MFMA(bf16x8 a, bf16x8 b, f32x4 c) {
    return __builtin_amdgcn_mfma_f32_16x16x32_bf16(a, b, c, 0, 0, 0);
}

// ---- prep: transpose weights to bf16 fragment-friendly layout in d_ws ----
// ws (ushort): WqT[512][64] @0, WkT @32768, WvT @65536, WpT[64][512] @98304  (256 KB)
// O buffer (two-kernel path): @131072 ushorts, [256*128][512] bf16 (32 MB)
extern "C" __global__ void geat_prep(const float* __restrict__ Wq,
                                     const float* __restrict__ Wk,
                                     const float* __restrict__ Wv,
                                     const float* __restrict__ Wp,
                                     ushort_t* __restrict__ ws)
{
    int idx = blockIdx.x * 256 + threadIdx.x;   // 0..131071
    int seg = idx >> 15;
    int r = idx & 32767;
    float v;
    if      (seg == 0) v = Wq[(r & 63) * 512 + (r >> 6)];    // WqT[o][d] = Wq[d][o]
    else if (seg == 1) v = Wk[(r & 63) * 512 + (r >> 6)];
    else if (seg == 2) v = Wv[(r & 63) * 512 + (r >> 6)];
    else               v = Wp[(r & 511) * 64 + (r >> 9)];    // WpT[c][k] = Wp[k][c]
    ws[idx] = f2bf(v);
}

// ============================================================================
// Kernel 1: per-(molecule, head) attention. Grid 2048, 256 thr (4 waves).
// XCD-locality (T1): b = bid & 255, h = bid >> 8  =>  all 8 head-blocks of
// molecule b have bid === b (mod 8) -> SAME XCD -> edges/x/weights are L2 hits
// after first touch (per-XCD set: 32*(64KB+32KB)+256KB ~= 3.3MB < 4MB L2).
// r7's b-major mapping put the 8 heads on 8 different XCDs: FETCH 98MB, 190us.
// Wave u owns rows 32u..32u+31. One barrier per block. LDS 48KB.
// ============================================================================
extern "C" __global__ __launch_bounds__(256, 1)
void geat_attn(const float* __restrict__ x, const int* __restrict__ edges,
               const float* __restrict__ bq, const float* __restrict__ bk,
               const float* __restrict__ bv, const float* __restrict__ ebias,
               const ushort_t* __restrict__ wt, ushort_t* __restrict__ ows)
{
    __shared__ __align__(16) ushort_t sm[24576];  // 48 KB
    ushort_t* QB  = sm;          // [128][64] Q, then P-half staging (wave-private rows)
    ushort_t* KB  = sm + 8192;   // [128][64] K (shared)
    ushort_t* VTB = sm + 16384;  // [64][128] V^T (shared)

    const int bid  = blockIdx.x;
    const int b    = bid & 255;         // T1: molecule selects the XCD (bid%8 == b%8)
    const int h    = bid >> 8;
    const int tid  = threadIdx.x;
    const int u    = tid >> 6;          // wave 0..3
    const int lane = tid & 63;
    const int c    = lane & 15;
    const int g    = lane >> 4;
    const int mu   = u * 32;            // wave's rows

    const ushort_t* WqT = wt;
    const ushort_t* WkT = wt + 32768;
    const ushort_t* WvT = wt + 65536;

    // ---- edge codes FIRST (longest-latency chains): (m = mu+16mf+4g+r, n = 16nt+c) ----
    unsigned epack[2][8];
    {
        const int* eg = edges + (size_t)b * NM * NM;
#pragma unroll
        for (int mf = 0; mf < 2; ++mf)
#pragma unroll
            for (int nt = 0; nt < 8; ++nt) {
                unsigned pk = 0;
#pragma unroll
                for (int r = 0; r < 4; ++r)
                    pk |= ((unsigned)eg[(mu + mf * 16 + 4 * g + r) * NM + nt * 16 + c] & 0xffu) << (8 * r);
                epack[mf][nt] = pk;
            }
    }

    // ---- x A-frags (2 m-frags x 2 k-chunks); double as x^T B-frags for V^T ----
    bf16x8 xA[2][2];
#pragma unroll
    for (int mf = 0; mf < 2; ++mf) {
        const float* xb = x + (size_t)b * NM * ND + (mu + mf * 16 + c) * ND;
#pragma unroll
        for (int kt = 0; kt < 2; ++kt) {
            const float4 lo = *(const float4*)&xb[kt * 32 + 8 * g];
            const float4 hi = *(const float4*)&xb[kt * 32 + 8 * g + 4];
            bf16x8 f;
            f[0] = f2bf(lo.x); f[1] = f2bf(lo.y); f[2] = f2bf(lo.z); f[3] = f2bf(lo.w);
            f[4] = f2bf(hi.x); f[5] = f2bf(hi.y); f[6] = f2bf(hi.z); f[7] = f2bf(hi.w);
            xA[mf][kt] = f;
        }
    }

    // ================= Phase A: Q, K (own 32 rows), V^T (own 32 cols) =================
#pragma unroll
    for (int mf = 0; mf < 2; ++mf) {
        int mt = mu + mf * 16;
#pragma unroll
        for (int nt4 = 0; nt4 < 4; ++nt4) {
            int n0 = nt4 * 16;
            f32x4 qacc = (f32x4)0.0f, kacc = (f32x4)0.0f;
#pragma unroll
            for (int kt = 0; kt < 2; ++kt) {
                const bf16x8 wq = *(const bf16x8*)&WqT[(h * 64 + n0 + c) * 64 + kt * 32 + 8 * g];
                const bf16x8 wk = *(const bf16x8*)&WkT[(h * 64 + n0 + c) * 64 + kt * 32 + 8 * g];
                qacc = MFMA(xA[mf][kt], wq, qacc);
                kacc = MFMA(xA[mf][kt], wk, kacc);
            }
            const float bqv = bq[h * 64 + n0 + c];
            const float bkv = bk[h * 64 + n0 + c];
#pragma unroll
            for (int r = 0; r < 4; ++r) {
                QB[sw64(mt + 4 * g + r, n0 + c)] = f2bf(qacc[r] + bqv);
                KB[sw64(mt + 4 * g + r, n0 + c)] = f2bf(kacc[r] + bkv);
            }
        }
    }
#pragma unroll
    for (int cf = 0; cf < 2; ++cf) {      // V^T cols mu+16cf .. +15
        int ct = mu + cf * 16;
#pragma unroll
        for (int dt = 0; dt < 4; ++dt) {
            int d0 = dt * 16;
            f32x4 vacc = (f32x4)0.0f;
#pragma unroll
            for (int kt = 0; kt < 2; ++kt) {
                const bf16x8 wv = *(const bf16x8*)&WvT[(h * 64 + d0 + c) * 64 + kt * 32 + 8 * g];
                vacc = MFMA(wv, xA[cf][kt], vacc);
            }
            const float4 bvv = *(const float4*)&bv[h * 64 + d0 + 4 * g];
#pragma unroll
            for (int r = 0; r < 4; ++r)
                VTB[sw128(d0 + 4 * g + r, ct + c)] = f2bf(vacc[r] + (&bvv.x)[r]);
        }
    }
    __syncthreads();   // the block's ONLY barrier: KB/VTB visible to all waves

    // ================= Phase B: S = QK^T/8 + bias, leaky, mask, softmax =================
    bf16x8 qA[2][2];
#pragma unroll
    for (int mf = 0; mf < 2; ++mf)
#pragma unroll
        for (int kt = 0; kt < 2; ++kt)
            qA[mf][kt] = *(const bf16x8*)&QB[sw64(mu + mf * 16 + c, kt * 32 + 8 * g)];

    float eb0 = ebias[0 * NH + h], eb1 = ebias[1 * NH + h], eb2 = ebias[2 * NH + h];
    float eb3 = ebias[3 * NH + h], eb4 = ebias[4 * NH + h];

    f32x4 s[2][8];
#pragma unroll
    for (int nt = 0; nt < 8; ++nt) {
        int n0 = nt * 16;
        bf16x8 kf[2];
#pragma unroll
        for (int kt = 0; kt < 2; ++kt)
            kf[kt] = *(const bf16x8*)&KB[sw64(n0 + c, kt * 32 + 8 * g)];
#pragma unroll
        for (int mf = 0; mf < 2; ++mf) {
            f32x4 acc = (f32x4)0.0f;
            acc = MFMA(qA[mf][0], kf[0], acc);
            acc = MFMA(qA[mf][1], kf[1], acc);
#pragma unroll
            for (int r = 0; r < 4; ++r) {
                int e = (epack[mf][nt] >> (8 * r)) & 0xff;
                float bias = (e == 1) ? eb1 : (e == 2) ? eb2 : (e == 3) ? eb3 : (e == 4) ? eb4 : eb0;
                float sv = acc[r] * 0.125f + bias;
                sv = (sv > 0.f) ? sv : 0.2f * sv;      // leaky BEFORE mask (ref order)
                acc[r] = (e > 0) ? sv : -1e9f;
            }
            s[mf][nt] = acc;
        }
    }
    // softmax per row (row = mu+16mf+4g+r): lane-local over nt, then 16-lane butterfly
    f32x4 inv[2];
#pragma unroll
    for (int mf = 0; mf < 2; ++mf) {
        f32x4 mx;
#pragma unroll
        for (int r = 0; r < 4; ++r) {
            float m0 = s[mf][0][r];
#pragma unroll
            for (int nt = 1; nt < 8; ++nt) m0 = fmaxf(m0, s[mf][nt][r]);
            mx[r] = m0;
        }
#pragma unroll
        for (int d = 1; d < 16; d <<= 1)
#pragma unroll
            for (int r = 0; r < 4; ++r) mx[r] = fmaxf(mx[r], __shfl_xor(mx[r], d));
        f32x4 sum = (f32x4)0.0f;
#pragma unroll
        for (int nt = 0; nt < 8; ++nt)
#pragma unroll
            for (int r = 0; r < 4; ++r) {
                float ev = __expf(s[mf][nt][r] - mx[r]);
                s[mf][nt][r] = ev;
                sum[r] += ev;
            }
#pragma unroll
        for (int d = 1; d < 16; d <<= 1)
#pragma unroll
            for (int r = 0; r < 4; ++r) sum[r] += __shfl_xor(sum[r], d);
#pragma unroll
        for (int r = 0; r < 4; ++r) inv[mf][r] = 1.f / sum[r];
    }

    // ================= Phase C: O = P·V in two half-passes (P staged in QB) =================
    f32x4 oacc[2][4];
#pragma unroll
    for (int mf = 0; mf < 2; ++mf)
#pragma unroll
        for (int dt = 0; dt < 4; ++dt) oacc[mf][dt] = (f32x4)0.0f;

#pragma unroll
    for (int half = 0; half < 2; ++half) {
#pragma unroll
        for (int mf = 0; mf < 2; ++mf)
#pragma unroll
            for (int nt = 0; nt < 4; ++nt)
#pragma unroll
                for (int r = 0; r < 4; ++r)
                    QB[sw64(mu + mf * 16 + 4 * g + r, nt * 16 + c)] =
                        f2bf(s[mf][half * 4 + nt][r] * inv[mf][r]);
        bf16x8 pA[2][2];
#pragma unroll
        for (int mf = 0; mf < 2; ++mf)
#pragma unroll
            for (int kt = 0; kt < 2; ++kt)
                pA[mf][kt] = *(const bf16x8*)&QB[sw64(mu + mf * 16 + c, kt * 32 + 8 * g)];
#pragma unroll
        for (int dt = 0; dt < 4; ++dt) {
            int d0 = dt * 16;
            bf16x8 vf[2];
#pragma unroll
            for (int kt = 0; kt < 2; ++kt)
                vf[kt] = *(const bf16x8*)&VTB[sw128(d0 + c, (half * 2 + kt) * 32 + 8 * g)];
#pragma unroll
            for (int mf = 0; mf < 2; ++mf) {
                oacc[mf][dt] = MFMA(pA[mf][0], vf[0], oacc[mf][dt]);
                oacc[mf][dt] = MFMA(pA[mf][1], vf[1], oacc[mf][dt]);
            }
        }
    }

    // ---- O D-frags -> ws O[b*128+m][512] at cols h*64 + d ----
#pragma unroll
    for (int mf = 0; mf < 2; ++mf)
#pragma unroll
        for (int dt = 0; dt < 4; ++dt)
#pragma unroll
            for (int r = 0; r < 4; ++r)
                ows[(((size_t)b * NM + mu + mf * 16 + 4 * g + r) << 9) + h * 64 + dt * 16 + c] =
                    f2bf(oacc[mf][dt][r]);
}

// ============================================================================
// Kernel 2: out = O[32768,512] @ Wp[512,64] + bp. Grid 512 (b, row-half), 256 thr.
// No LDS, no barriers; A/B frags straight from global (L2/L3-resident).
// ============================================================================
extern "C" __global__ __launch_bounds__(256, 1)
void geat_oproj(const ushort_t* __restrict__ ows, const ushort_t* __restrict__ wt,
                const float* __restrict__ bp, float* __restrict__ out)
{
    const ushort_t* WpT = wt + 98304;
    const int bid  = blockIdx.x;
    const int b    = bid >> 1;
    const int rh   = bid & 1;
    const int tid  = threadIdx.x;
    const int u    = tid >> 6;
    const int lane = tid & 63;
    const int c    = lane & 15;
    const int g    = lane >> 4;
    const int mt   = rh * 64 + u * 16;   // wave's 16 rows

    f32x4 acc[4];
#pragma unroll
    for (int nt4 = 0; nt4 < 4; ++nt4) {
        float bpv = bp[nt4 * 16 + c];
        acc[nt4] = (f32x4){bpv, bpv, bpv, bpv};
    }
    const ushort_t* orow = ows + (((size_t)b * NM + mt + c) << 9);
#pragma unroll
    for (int kt = 0; kt < 16; ++kt) {
        const bf16x8 oA = *(const bf16x8*)&orow[kt * 32 + 8 * g];
#pragma unroll
        for (int nt4 = 0; nt4 < 4; ++nt4) {
            const bf16x8 wp = *(const bf16x8*)&WpT[(nt4 * 16 + c) * 512 + kt * 32 + 8 * g];
            acc[nt4] = MFMA(oA, wp, acc[nt4]);
        }
    }
    float* og = out + (size_t)b * NM * ND;
#pragma unroll
    for (int nt4 = 0; nt4 < 4; ++nt4)
#pragma unroll
        for (int r = 0; r < 4; ++r)
            og[(mt + 4 * g + r) * ND + nt4 * 16 + c] = acc[nt4][r];
}

// ============================================================================
// Fallback (round-6 fused, proven 133.8us): used only if ws too small.
// ============================================================================
extern "C" __global__ __launch_bounds__(512, 1)
void geat_mfma(const float* __restrict__ x, const int* __restrict__ edges,
               const float* __restrict__ bq, const float* __restrict__ bk,
               const float* __restrict__ bv, const float* __restrict__ ebias,
               const float* __restrict__ bp, const ushort_t* __restrict__ wt,
               float* __restrict__ out)
{
    __shared__ __align__(16) ushort_t sm[32768];
    ushort_t* QB  = sm;
    ushort_t* KB  = sm + 8192;
    ushort_t* VTB = sm + 16384;
    ushort_t* PB  = sm + 24576;

    const int b    = blockIdx.x;
    const int tid  = threadIdx.x;
    const int lane = tid & 63;
    const int c    = lane & 15;
    const int g    = lane >> 4;
    const int mt   = (tid >> 6) * 16;

    const ushort_t* WqT = wt;
    const ushort_t* WkT = wt + 32768;
    const ushort_t* WvT = wt + 65536;
    const ushort_t* WpT = wt + 98304;

    bf16x8 xA[2];
    {
        const float* xb = x + (size_t)b * NM * ND + (mt + c) * ND;
#pragma unroll
        for (int kt = 0; kt < 2; ++kt) {
            const float4 lo = *(const float4*)&xb[kt * 32 + 8 * g];
            const float4 hi = *(const float4*)&xb[kt * 32 + 8 * g + 4];
            bf16x8 f;
            f[0] = f2bf(lo.x); f[1] = f2bf(lo.y); f[2] = f2bf(lo.z); f[3] = f2bf(lo.w);
            f[4] = f2bf(hi.x); f[5] = f2bf(hi.y); f[6] = f2bf(hi.z); f[7] = f2bf(hi.w);
            xA[kt] = f;
        }
    }
    unsigned epack[8];
    {
        const int* eg = edges + (size_t)b * NM * NM;
#pragma unroll
        for (int nt = 0; nt < 8; ++nt) {
            unsigned pk = 0;
#pragma unroll
            for (int r = 0; r < 4; ++r)
                pk |= ((unsigned)eg[(mt + 4 * g + r) * NM + nt * 16 + c] & 0xffu) << (8 * r);
            epack[nt] = pk;
        }
    }
    f32x4 projacc[4];
#pragma unroll
    for (int i = 0; i < 4; ++i) projacc[i] = (f32x4)0.0f;

#pragma unroll 1
    for (int h = 0; h < NH; ++h) {
#pragma unroll
        for (int nt4 = 0; nt4 < 4; ++nt4) {
            int n0 = nt4 * 16;
            float bqv = bq[h * 64 + n0 + c];
            float bkv = bk[h * 64 + n0 + c];
            f32x4 qacc = {bqv, bqv, bqv, bqv};
            f32x4 kacc = {bkv, bkv, bkv, bkv};
#pragma unroll
            for (int kt = 0; kt < 2; ++kt) {
                const bf16x8 wq = *(const bf16x8*)&WqT[(h * 64 + n0 + c) * 64 + kt * 32 + 8 * g];
                const bf16x8 wk = *(const bf16x8*)&WkT[(h * 64 + n0 + c) * 64 + kt * 32 + 8 * g];
                qacc = MFMA(xA[kt], wq, qacc);
                kacc = MFMA(xA[kt], wk, kacc);
            }
#pragma unroll
            for (int r = 0; r < 4; ++r) {
                QB[sw64(mt + 4 * g + r, n0 + c)] = f2bf(qacc[r]);
                KB[sw64(mt + 4 * g + r, n0 + c)] = f2bf(kacc[r]);
            }
        }
#pragma unroll
        for (int dt = 0; dt < 4; ++dt) {
            int d0 = dt * 16;
            f32x4 vacc;
#pragma unroll
            for (int r = 0; r < 4; ++r) vacc[r] = bv[h * 64 + d0 + 4 * g + r];
#pragma unroll
            for (int kt = 0; kt < 2; ++kt) {
                const bf16x8 wv = *(const bf16x8*)&WvT[(h * 64 + d0 + c) * 64 + kt * 32 + 8 * g];
                vacc = MFMA(wv, xA[kt], vacc);
            }
#pragma unroll
            for (int r = 0; r < 4; ++r)
                VTB[sw128(d0 + 4 * g + r, mt + c)] = f2bf(vacc[r]);
        }
        __syncthreads();

        bf16x8 qA[2];
#pragma unroll
        for (int kt = 0; kt < 2; ++kt)
            qA[kt] = *(const bf16x8*)&QB[sw64(mt + c, kt * 32 + 8 * g)];

        float eb0 = ebias[0 * NH + h], eb1 = ebias[1 * NH + h], eb2 = ebias[2 * NH + h];
        float eb3 = ebias[3 * NH + h], eb4 = ebias[4 * NH + h];

        f32x4 s[8];
#pragma unroll
        for (int nt = 0; nt < 8; ++nt) {
            int n0 = nt * 16;
            f32x4 acc = (f32x4)0.0f;
#pragma unroll
            for (int kt = 0; kt < 2; ++kt) {
                const bf16x8 kf = *(const bf16x8*)&KB[sw64(n0 + c, kt * 32 + 8 * g)];
                acc = MFMA(qA[kt], kf, acc);
            }
#pragma unroll
            for (int r = 0; r < 4; ++r) {
                int e = (epack[nt] >> (8 * r)) & 0xff;
                float bias = (e == 1) ? eb1 : (e == 2) ? eb2 : (e == 3) ? eb3 : (e == 4) ? eb4 : eb0;
                float sv = acc[r] * 0.125f + bias;
                sv = (sv > 0.f) ? sv : 0.2f * sv;
                acc[r] = (e > 0) ? sv : -1e9f;
            }
            s[nt] = acc;
        }
        f32x4 mx;
#pragma unroll
        for (int r = 0; r < 4; ++r) {
            float m0 = s[0][r];
#pragma unroll
            for (int nt = 1; nt < 8; ++nt) m0 = fmaxf(m0, s[nt][r]);
            mx[r] = m0;
        }
#pragma unroll
        for (int d = 1; d < 16; d <<= 1)
#pragma unroll
            for (int r = 0; r < 4; ++r) mx[r] = fmaxf(mx[r], __shfl_xor(mx[r], d));
        f32x4 sum = (f32x4)0.0f;
#pragma unroll
        for (int nt = 0; nt < 8; ++nt)
#pragma unroll
            for (int r = 0; r < 4; ++r) {
                float ev = __expf(s[nt][r] - mx[r]);
                s[nt][r] = ev;
                sum[r] += ev;
            }
#pragma unroll
        for (int d = 1; d < 16; d <<= 1)
#pragma unroll
            for (int r = 0; r < 4; ++r) sum[r] += __shfl_xor(sum[r], d);
        f32x4 inv;
#pragma unroll
        for (int r = 0; r < 4; ++r) inv[r] = 1.f / sum[r];

        f32x4 oacc[4];
#pragma unroll
        for (int dt = 0; dt < 4; ++dt) oacc[dt] = (f32x4)0.0f;
#pragma unroll
        for (int half = 0; half < 2; ++half) {
#pragma unroll
            for (int nt = 0; nt < 4; ++nt)
#pragma unroll
                for (int r = 0; r < 4; ++r)
                    PB[sw64(mt + 4 * g + r, nt * 16 + c)] = f2bf(s[half * 4 + nt][r] * inv[r]);
            bf16x8 pA[2];
#pragma unroll
            for (int kt = 0; kt < 2; ++kt)
                pA[kt] = *(const bf16x8*)&PB[sw64(mt + c, kt * 32 + 8 * g)];
#pragma unroll
            for (int dt = 0; dt < 4; ++dt) {
                int d0 = dt * 16;
#pragma unroll
                for (int kt = 0; kt < 2; ++kt) {
                    const bf16x8 vf = *(const bf16x8*)&VTB[sw128(d0 + c, (half * 2 + kt) * 32 + 8 * g)];
                    oacc[dt] = MFMA(pA[kt], vf, oacc[dt]);
                }
            }
        }
#pragma unroll
        for (int dt = 0; dt < 4; ++dt)
#pragma unroll
            for (int r = 0; r < 4; ++r)
                QB[sw64(mt + 4 * g + r, dt * 16 + c)] = f2bf(oacc[dt][r]);

        bf16x8 oA[2];
#pragma unroll
        for (int kt = 0; kt < 2; ++kt)
            oA[kt] = *(const bf16x8*)&QB[sw64(mt + c, kt * 32 + 8 * g)];
#pragma unroll
        for (int nt4 = 0; nt4 < 4; ++nt4) {
            int n0 = nt4 * 16;
#pragma unroll
            for (int kt = 0; kt < 2; ++kt) {
                const bf16x8 wp = *(const bf16x8*)&WpT[(n0 + c) * 512 + h * 64 + kt * 32 + 8 * g];
                projacc[nt4] = MFMA(oA[kt], wp, projacc[nt4]);
            }
        }
        __syncthreads();
    }
    {
        float* og = out + (size_t)b * NM * ND;
#pragma unroll
        for (int nt4 = 0; nt4 < 4; ++nt4) {
            int n0 = nt4 * 16;
            float bpv = bp[n0 + c];
#pragma unroll
            for (int r = 0; r < 4; ++r)
                og[(mt + 4 * g + r) * ND + n0 + c] = projacc[nt4][r] + bpv;
        }
    }
}

extern "C" void kernel_launch(void* const* d_in, const int* in_sizes, int n_in,
                              void* d_out, int out_size, void* d_ws, size_t ws_size,
                              hipStream_t stream) {
    const float* x     = (const float*)d_in[0];
    const int*   edges = (const int*)d_in[1];
    const float* Wq    = (const float*)d_in[2];
    const float* bq    = (const float*)d_in[3];
    const float* Wk    = (const float*)d_in[4];
    const float* bk    = (const float*)d_in[5];
    const float* Wv    = (const float*)d_in[6];
    const float* bv    = (const float*)d_in[7];
    const float* eb    = (const float*)d_in[8];
    const float* Wp    = (const float*)d_in[9];
    const float* bp    = (const float*)d_in[10];
    float* out = (float*)d_out;
    ushort_t* ws = (ushort_t*)d_ws;

    hipLaunchKernelGGL(geat_prep, dim3(512), dim3(256), 0, stream, Wq, Wk, Wv, Wp, ws);

    const size_t need = 262144u + (size_t)NB * NM * 512 * sizeof(ushort_t);  // 33.8 MB
    if (ws_size >= need) {
        ushort_t* oexp = ws + 131072;   // O buffer after the weight block
        hipLaunchKernelGGL(geat_attn, dim3(NB * NH), dim3(256), 0, stream,
                           x, edges, bq, bk, bv, eb, ws, oexp);
        hipLaunchKernelGGL(geat_oproj, dim3(NB * 2), dim3(256), 0, stream,
                           oexp, ws, bp, out);
    } else {
        hipLaunchKernelGGL(geat_mfma, dim3(NB), dim3(512), 0, stream,
                           x, edges, bq, bk, bv, eb, bp, ws, out);
    }
}

// Round 10
// 144.245 us; speedup vs baseline: 1.3953x; 1.3953x over previous
//
#include <hip/hip_runtime.h>

#define NB 256
#define NM 128
#define ND 64
#define NH 8

typedef float f32x4 __attribute__((ext_vector_type(4)));
typedef short bf16x8 __attribute__((ext_vector_type(8)));   // 8 bf16 = 4 VGPRs
typedef unsigned short ushort_t;

__device__ __forceinline__ ushort_t f2bf(float f) {   // RNE f32->bf16
    unsigned int x = __float_as_uint(f);
    x += 0x7fffu + ((x >> 16) & 1u);
    return (ushort_t)(x >> 16);
}
__device__ __forceinline__ unsigned pk2(float a, float b) {
    return (unsigned)f2bf(a) | ((unsigned)f2bf(b) << 16);
}

// XOR-swizzled LDS indices (T2): col ^= 8*(row&7), both write and read.
// b64 writes cover 4-elem chunks at 4-aligned cols: XOR by multiples of 8
// permutes 8-blocks and preserves 4-sub-blocks -> contiguity + alignment hold.
__device__ __forceinline__ int sw64(int row, int col)  { return row * 64  + (col ^ ((row & 7) << 3)); }
__device__ __forceinline__ int sw128(int row, int col) { return row * 128 + (col ^ ((row & 7) << 3)); }

__device__ __forceinline__ f32x4 MFMA(bf16x8 a, bf16x8 b, f32x4 c) {
    return __builtin_amdgcn_mfma_f32_16x16x32_bf16(a, b, c, 0, 0, 0);
}

// ---- prep: transpose weights to bf16 fragment layout in d_ws ----
// ws (ushort): WqT[512][64] @0, WkT @32768, WvT @65536, WpT[64][512] @98304 (256 KB)
extern "C" __global__ void geat_prep(const float* __restrict__ Wq,
                                     const float* __restrict__ Wk,
                                     const float* __restrict__ Wv,
                                     const float* __restrict__ Wp,
                                     ushort_t* __restrict__ ws)
{
    int idx = blockIdx.x * 256 + threadIdx.x;   // 0..131071
    int seg = idx >> 15;
    int r = idx & 32767;
    float v;
    if      (seg == 0) v = Wq[(r & 63) * 512 + (r >> 6)];    // WqT[o][d] = Wq[d][o]
    else if (seg == 1) v = Wk[(r & 63) * 512 + (r >> 6)];
    else if (seg == 2) v = Wv[(r & 63) * 512 + (r >> 6)];
    else               v = Wp[(r & 511) * 64 + (r >> 9)];    // WpT[c][k] = Wp[k][c]
    ws[idx] = f2bf(v);
}

// ============================================================================
// Fused kernel, r6 chassis + two levers:
//  (1) b64 staging: Q^T/K^T via swapped-operand MFMA + transposed store,
//      V via normal MFMA + transposed store -> 12 ds_write_b64 (was 48 b16).
//  (2) PROJ(h+1) into the other LDS buffer runs IN THE SAME barrier region as
//      ATTN(h) -> weight-load latency hides under attention; 1 barrier/head.
//      Weight frags are consumed in-phase (short live range, no r8-style spill).
// Grid 256 (1 block/CU), 512 thr. LDS 96 KB. DO NOT pass a min-waves hint
// (compiler caps VGPRs at 256/min_waves: r2/r5 evidence).
// ============================================================================
extern "C" __global__ __launch_bounds__(512, 1)
void geat_pipe(const float* __restrict__ x, const int* __restrict__ edges,
               const float* __restrict__ bq, const float* __restrict__ bk,
               const float* __restrict__ bv, const float* __restrict__ ebias,
               const float* __restrict__ bp, const ushort_t* __restrict__ wt,
               float* __restrict__ out)
{
    __shared__ __align__(16) ushort_t sm[49152];  // 2 x {QB 8192, KB 8192, VTB 8192} ushorts

    const int b    = blockIdx.x;
    const int tid  = threadIdx.x;
    const int lane = tid & 63;
    const int c    = lane & 15;
    const int g    = lane >> 4;
    const int mt   = (tid >> 6) * 16;   // wave's 16 token rows

    const ushort_t* WqT = wt;
    const ushort_t* WkT = wt + 32768;
    const ushort_t* WvT = wt + 65536;
    const ushort_t* WpT = wt + 98304;

    // ---- x frags for own rows (A-frag: rows mt+c; B-frag: cols mt+c) ----
    bf16x8 xA[2];
    {
        const float* xb = x + (size_t)b * NM * ND + (mt + c) * ND;
#pragma unroll
        for (int kt = 0; kt < 2; ++kt) {
            const float4 lo = *(const float4*)&xb[kt * 32 + 8 * g];
            const float4 hi = *(const float4*)&xb[kt * 32 + 8 * g + 4];
            bf16x8 f;
            f[0] = f2bf(lo.x); f[1] = f2bf(lo.y); f[2] = f2bf(lo.z); f[3] = f2bf(lo.w);
            f[4] = f2bf(hi.x); f[5] = f2bf(hi.y); f[6] = f2bf(hi.z); f[7] = f2bf(hi.w);
            xA[kt] = f;
        }
    }

    // ---- edge codes, head-invariant: (m = mt+4g+r, n = 16nt+c), packed 4x8b ----
    unsigned epack[8];
    {
        const int* eg = edges + (size_t)b * NM * NM;
#pragma unroll
        for (int nt = 0; nt < 8; ++nt) {
            unsigned pk = 0;
#pragma unroll
            for (int r = 0; r < 4; ++r)
                pk |= ((unsigned)eg[(mt + 4 * g + r) * NM + nt * 16 + c] & 0xffu) << (8 * r);
            epack[nt] = pk;
        }
    }

    f32x4 projacc[4];
#pragma unroll
    for (int i = 0; i < 4; ++i) projacc[i] = (f32x4)0.0f;

    // PROJ: project head h2's Q,K,V for this wave's 16 rows into buf.
    //  Q^T = mfma(WqT-frag, xA)  -> D(d'=d0+4g+r, m=mt+c) -> QB[m][d'] b64
    //  K^T = mfma(WkT-frag, xA)  -> KB[token][d'] b64
    //  V   = mfma(xA, WvT-frag)  -> D(n=mt+4g+r, d'=d0+c) -> VTB[d'][n] b64
    auto PROJ = [&](int h2, ushort_t* buf) {
        ushort_t* QBn = buf;
        ushort_t* KBn = buf + 8192;
        ushort_t* VTn = buf + 16384;
#pragma unroll
        for (int dt = 0; dt < 4; ++dt) {
            const int d0 = dt * 16;
            f32x4 qT = (f32x4)0.0f, kT = (f32x4)0.0f, vn = (f32x4)0.0f;
#pragma unroll
            for (int kt = 0; kt < 2; ++kt) {
                const int woff = (h2 * 64 + d0 + c) * 64 + kt * 32 + 8 * g;
                const bf16x8 wq = *(const bf16x8*)&WqT[woff];
                const bf16x8 wk = *(const bf16x8*)&WkT[woff];
                const bf16x8 wv = *(const bf16x8*)&WvT[woff];
                qT = MFMA(wq, xA[kt], qT);
                kT = MFMA(wk, xA[kt], kT);
                vn = MFMA(xA[kt], wv, vn);
            }
            const float4 bqv = *(const float4*)&bq[h2 * 64 + d0 + 4 * g];
            const float4 bkv = *(const float4*)&bk[h2 * 64 + d0 + 4 * g];
            const float  bvv = bv[h2 * 64 + d0 + c];
            uint2 qp, kp, vp;
            qp.x = pk2(qT[0] + bqv.x, qT[1] + bqv.y);
            qp.y = pk2(qT[2] + bqv.z, qT[3] + bqv.w);
            kp.x = pk2(kT[0] + bkv.x, kT[1] + bkv.y);
            kp.y = pk2(kT[2] + bkv.z, kT[3] + bkv.w);
            vp.x = pk2(vn[0] + bvv, vn[1] + bvv);
            vp.y = pk2(vn[2] + bvv, vn[3] + bvv);
            *(uint2*)&QBn[sw64(mt + c, d0 + 4 * g)] = qp;
            *(uint2*)&KBn[sw64(mt + c, d0 + 4 * g)] = kp;
            *(uint2*)&VTn[sw128(d0 + c, mt + 4 * g)] = vp;
        }
    };

    // ---- prologue: head 0 into buffer 0 ----
    PROJ(0, sm);
    __syncthreads();

#pragma unroll 1
    for (int h = 0; h < NH; ++h) {
        ushort_t* bufc = sm + (h & 1) * 24576;
        ushort_t* bufn = sm + ((h & 1) ^ 1) * 24576;
        ushort_t* QBc  = bufc;
        ushort_t* KBc  = bufc + 8192;
        ushort_t* VTc  = bufc + 16384;

        // own-row Q A-frags (before P staging overwrites QBc)
        bf16x8 qA[2];
#pragma unroll
        for (int kt = 0; kt < 2; ++kt)
            qA[kt] = *(const bf16x8*)&QBc[sw64(mt + c, kt * 32 + 8 * g)];

        // pipeline: project next head into the other buffer inside THIS region
        if (h < NH - 1) PROJ(h + 1, bufn);

        const float eb0 = ebias[0 * NH + h], eb1 = ebias[1 * NH + h], eb2 = ebias[2 * NH + h];
        const float eb3 = ebias[3 * NH + h], eb4 = ebias[4 * NH + h];

        // ---- S = QK^T/8 + bias, leaky, mask ----
        f32x4 s[8];
#pragma unroll
        for (int nt = 0; nt < 8; ++nt) {
            const int n0 = nt * 16;
            f32x4 acc = (f32x4)0.0f;
#pragma unroll
            for (int kt = 0; kt < 2; ++kt) {
                const bf16x8 kf = *(const bf16x8*)&KBc[sw64(n0 + c, kt * 32 + 8 * g)];
                acc = MFMA(qA[kt], kf, acc);
            }
#pragma unroll
            for (int r = 0; r < 4; ++r) {
                const int e = (epack[nt] >> (8 * r)) & 0xff;
                const float bias = (e == 1) ? eb1 : (e == 2) ? eb2 : (e == 3) ? eb3 : (e == 4) ? eb4 : eb0;
                float sv = acc[r] * 0.125f + bias;
                sv = (sv > 0.f) ? sv : 0.2f * sv;      // leaky BEFORE mask (ref order)
                acc[r] = (e > 0) ? sv : -1e9f;
            }
            s[nt] = acc;
        }

        // ---- softmax per row: lane-local over nt, then 16-lane butterfly ----
        f32x4 mx;
#pragma unroll
        for (int r = 0; r < 4; ++r) {
            float m0 = s[0][r];
#pragma unroll
            for (int nt = 1; nt < 8; ++nt) m0 = fmaxf(m0, s[nt][r]);
            mx[r] = m0;
        }
#pragma unroll
        for (int d = 1; d < 16; d <<= 1)
#pragma unroll
            for (int r = 0; r < 4; ++r) mx[r] = fmaxf(mx[r], __shfl_xor(mx[r], d));
        f32x4 sum = (f32x4)0.0f;
#pragma unroll
        for (int nt = 0; nt < 8; ++nt)
#pragma unroll
            for (int r = 0; r < 4; ++r) {
                const float ev = __expf(s[nt][r] - mx[r]);
                s[nt][r] = ev;
                sum[r] += ev;
            }
#pragma unroll
        for (int d = 1; d < 16; d <<= 1)
#pragma unroll
            for (int r = 0; r < 4; ++r) sum[r] += __shfl_xor(sum[r], d);
        f32x4 inv;
#pragma unroll
        for (int r = 0; r < 4; ++r) inv[r] = 1.f / sum[r];

        // ---- O = P·V in two half-passes, P staged in QBc (Q dead; rows wave-private) ----
        f32x4 oacc[4];
#pragma unroll
        for (int dt = 0; dt < 4; ++dt) oacc[dt] = (f32x4)0.0f;
#pragma unroll
        for (int half = 0; half < 2; ++half) {
#pragma unroll
            for (int nt = 0; nt < 4; ++nt)
#pragma unroll
                for (int r = 0; r < 4; ++r)
                    QBc[sw64(mt + 4 * g + r, nt * 16 + c)] = f2bf(s[half * 4 + nt][r] * inv[r]);
            bf16x8 pA[2];
#pragma unroll
            for (int kt = 0; kt < 2; ++kt)
                pA[kt] = *(const bf16x8*)&QBc[sw64(mt + c, kt * 32 + 8 * g)];
#pragma unroll
            for (int dt = 0; dt < 4; ++dt) {
                const int d0 = dt * 16;
#pragma unroll
                for (int kt = 0; kt < 2; ++kt) {
                    const bf16x8 vf = *(const bf16x8*)&VTc[sw128(d0 + c, (half * 2 + kt) * 32 + 8 * g)];
                    oacc[dt] = MFMA(pA[kt], vf, oacc[dt]);
                }
            }
        }

        // ---- stage O rows (reuse QBc), out-proj accumulate ----
#pragma unroll
        for (int dt = 0; dt < 4; ++dt)
#pragma unroll
            for (int r = 0; r < 4; ++r)
                QBc[sw64(mt + 4 * g + r, dt * 16 + c)] = f2bf(oacc[dt][r]);
        bf16x8 oA[2];
#pragma unroll
        for (int kt = 0; kt < 2; ++kt)
            oA[kt] = *(const bf16x8*)&QBc[sw64(mt + c, kt * 32 + 8 * g)];
#pragma unroll
        for (int nt4 = 0; nt4 < 4; ++nt4) {
            const int n0 = nt4 * 16;
#pragma unroll
            for (int kt = 0; kt < 2; ++kt) {
                const bf16x8 wp = *(const bf16x8*)&WpT[(n0 + c) * 512 + h * 64 + kt * 32 + 8 * g];
                projacc[nt4] = MFMA(oA[kt], wp, projacc[nt4]);
            }
        }

        __syncthreads();   // one barrier per head: bufn ready, bufc free
    }

    // ---- epilogue: + bp, coalesced f32 stores ----
    {
        float* og = out + (size_t)b * NM * ND;
#pragma unroll
        for (int nt4 = 0; nt4 < 4; ++nt4) {
            const int n0 = nt4 * 16;
            const float bpv = bp[n0 + c];
#pragma unroll
            for (int r = 0; r < 4; ++r)
                og[(mt + 4 * g + r) * ND + n0 + c] = projacc[nt4][r] + bpv;
        }
    }
}

extern "C" void kernel_launch(void* const* d_in, const int* in_sizes, int n_in,
                              void* d_out, int out_size, void* d_ws, size_t ws_size,
                              hipStream_t stream) {
    const float* x     = (const float*)d_in[0];
    const int*   edges = (const int*)d_in[1];
    const float* Wq    = (const float*)d_in[2];
    const float* bq    = (const float*)d_in[3];
    const float* Wk    = (const float*)d_in[4];
    const float* bk    = (const float*)d_in[5];
    const float* Wv    = (const float*)d_in[6];
    const float* bv    = (const float*)d_in[7];
    const float* eb    = (const float*)d_in[8];
    const float* Wp    = (const float*)d_in[9];
    const float* bp    = (const float*)d_in[10];
    float* out = (float*)d_out;
    ushort_t* ws = (ushort_t*)d_ws;   // needs 262144 B

    hipLaunchKernelGGL(geat_prep, dim3(512), dim3(256), 0, stream, Wq, Wk, Wv, Wp, ws);
    hipLaunchKernelGGL(geat_pipe, dim3(NB), dim3(512), 0, stream,
                       x, edges, bq, bk, bv, eb, bp, ws, out);
}

// Round 11
// 141.972 us; speedup vs baseline: 1.4176x; 1.0160x over previous
//
#include <hip/hip_runtime.h>

#define NB 256
#define NM 128
#define ND 64
#define NH 8

typedef float f32x4 __attribute__((ext_vector_type(4)));
typedef short bf16x8 __attribute__((ext_vector_type(8)));   // 8 bf16 = 4 VGPRs (16x16x32 A/B)
typedef short bf16x4 __attribute__((ext_vector_type(4)));   // 4 bf16 = 2 VGPRs (16x16x16 A/B)
typedef unsigned short ushort_t;

__device__ __forceinline__ ushort_t f2bf(float f) {   // RNE f32->bf16
    unsigned int x = __float_as_uint(f);
    x += 0x7fffu + ((x >> 16) & 1u);
    return (ushort_t)(x >> 16);
}
__device__ __forceinline__ unsigned pk2(float a, float b) {
    return (unsigned)f2bf(a) | ((unsigned)f2bf(b) << 16);
}
__device__ __forceinline__ bf16x4 pk4(float a, float b, float c, float d) {
    bf16x4 t;
    t[0] = (short)f2bf(a); t[1] = (short)f2bf(b);
    t[2] = (short)f2bf(c); t[3] = (short)f2bf(d);
    return t;
}
__device__ __forceinline__ f32x4 vmax4(f32x4 a, f32x4 b) {
    f32x4 r;
#pragma unroll
    for (int i = 0; i < 4; ++i) r[i] = fmaxf(a[i], b[i]);
    return r;
}

// XOR-swizzled LDS indices (T2): col ^= 8*(row&7), write and read. XOR by
// multiples of 8 elements preserves 4-aligned b64 chunks (4g mod 8 in {0,4}).
__device__ __forceinline__ int sw64(int row, int col)  { return row * 64  + (col ^ ((row & 7) << 3)); }
__device__ __forceinline__ int sw128(int row, int col) { return row * 128 + (col ^ ((row & 7) << 3)); }

__device__ __forceinline__ f32x4 MFMA(bf16x8 a, bf16x8 b, f32x4 c) {
    return __builtin_amdgcn_mfma_f32_16x16x32_bf16(a, b, c, 0, 0, 0);
}

// 16x16x16 bf16 MFMA: A/B = 4 bf16/lane (lane(c,g): row/col=c, k=4g+j).
#if defined(__has_builtin)
#if __has_builtin(__builtin_amdgcn_mfma_f32_16x16x16bf16_1k)
#define HAVE_MFMA16 1
__device__ __forceinline__ f32x4 MFMA16(bf16x4 a, bf16x4 b, f32x4 c) {
    return __builtin_amdgcn_mfma_f32_16x16x16bf16_1k(a, b, c, 0, 0, 0);
}
#endif
#endif
#ifndef HAVE_MFMA16
__device__ __forceinline__ f32x4 MFMA16(bf16x4 a, bf16x4 b, f32x4 c) {
    f32x4 d;
    asm volatile("v_mfma_f32_16x16x16_bf16 %0, %1, %2, %3\n\ts_nop 7\n\ts_nop 7"
                 : "=v"(d) : "v"(a), "v"(b), "v"(c));
    return d;
}
#endif

// ---- prep: transpose weights to bf16 fragment layout in d_ws ----
// ws (ushort): WqT[512][64] @0, WkT @32768, WvT @65536, WpT[64][512] @98304 (256 KB)
extern "C" __global__ void geat_prep(const float* __restrict__ Wq,
                                     const float* __restrict__ Wk,
                                     const float* __restrict__ Wv,
                                     const float* __restrict__ Wp,
                                     ushort_t* __restrict__ ws)
{
    int idx = blockIdx.x * 256 + threadIdx.x;   // 0..131071
    int seg = idx >> 15;
    int r = idx & 32767;
    float v;
    if      (seg == 0) v = Wq[(r & 63) * 512 + (r >> 6)];    // WqT[o][d] = Wq[d][o]
    else if (seg == 1) v = Wk[(r & 63) * 512 + (r >> 6)];
    else if (seg == 2) v = Wv[(r & 63) * 512 + (r >> 6)];
    else               v = Wp[(r & 511) * 64 + (r >> 9)];    // WpT[c][k] = Wp[k][c]
    ws[idx] = f2bf(v);
}

// ============================================================================
// Swapped-S all-register attention. Grid 256 (1 block/CU), 512 thr (8 waves,
// wave w owns token rows 16w..16w+15; lane (c,g) owns full score row mt+c).
//  - S^T = mfma16(K-granule, Q-granule): lane holds S[mt+c][n] in 4-granules.
//  - softmax in-register: tree + 2 shuffles (xor16/32). No P LDS round-trip.
//  - PV: O = mfma16(VT-granule, P-granule) -> O[mt+c][d] granules in regs.
//  - oproj: mfma16(O-granule, WpT-granule) -> projacc. No O LDS round-trip.
//  - Q stays in registers (8 VGPR), double-set across the PROJ pipeline.
// LDS 64 KB (K + V^T only, double-buffered); 1 barrier/head; PROJ(h+1)
// overlaps ATTN(h). DO NOT pass a min-waves launch-bounds hint (r2/r5: the
// compiler caps VGPRs at 256/min_waves and spills).
// ============================================================================
extern "C" __global__ __launch_bounds__(512, 1)
void geat_pipe(const float* __restrict__ x, const int* __restrict__ edges,
               const float* __restrict__ bq, const float* __restrict__ bk,
               const float* __restrict__ bv, const float* __restrict__ ebias,
               const float* __restrict__ bp, const ushort_t* __restrict__ wt,
               float* __restrict__ out)
{
    __shared__ __align__(16) ushort_t sm[32768];  // 64 KB: 2 x {KB 8192, VTB 8192} ushorts

    const int b    = blockIdx.x;
    const int tid  = threadIdx.x;
    const int lane = tid & 63;
    const int c    = lane & 15;
    const int g    = lane >> 4;
    const int mt   = (tid >> 6) * 16;   // wave's 16 token rows

    const ushort_t* WqT = wt;
    const ushort_t* WkT = wt + 32768;
    const ushort_t* WvT = wt + 65536;
    const ushort_t* WpT = wt + 98304;

    // ---- x frags for own rows (A-frag rows mt+c / B-frag cols mt+c) ----
    bf16x8 xA[2];
    {
        const float* xb = x + (size_t)b * NM * ND + (mt + c) * ND;
#pragma unroll
        for (int kt = 0; kt < 2; ++kt) {
            const float4 lo = *(const float4*)&xb[kt * 32 + 8 * g];
            const float4 hi = *(const float4*)&xb[kt * 32 + 8 * g + 4];
            bf16x8 f;
            f[0] = f2bf(lo.x); f[1] = f2bf(lo.y); f[2] = f2bf(lo.z); f[3] = f2bf(lo.w);
            f[4] = f2bf(hi.x); f[5] = f2bf(hi.y); f[6] = f2bf(hi.z); f[7] = f2bf(hi.w);
            xA[kt] = f;
        }
    }

    // ---- edge codes for row mt+c: n = 16nt+4g+r, packed 4x8b per nt ----
    unsigned epack[8];
    {
        const int* erow = edges + (size_t)b * NM * NM + (mt + c) * NM;
#pragma unroll
        for (int nt = 0; nt < 8; ++nt) {
            const int4 e4 = *(const int4*)&erow[nt * 16 + 4 * g];
            epack[nt] = (unsigned)(e4.x & 0xff) | ((unsigned)(e4.y & 0xff) << 8) |
                        ((unsigned)(e4.z & 0xff) << 16) | ((unsigned)(e4.w & 0xff) << 24);
        }
    }

    f32x4 projacc[4];
#pragma unroll
    for (int i = 0; i < 4; ++i) projacc[i] = (f32x4)0.0f;

    bf16x4 qcur[4], qnext[4];   // Q[mt+c][16kt+4g+j], j=0..3 — B-granules for S

    // PROJ head h2: K -> KB[token][d] (b64), V^T -> VTB[d][token] (b64),
    // Q -> qout granules (registers only).
    auto PROJ = [&](int h2, ushort_t* buf, bf16x4* qout) {
        ushort_t* KBn = buf;
        ushort_t* VTn = buf + 8192;
#pragma unroll
        for (int dt = 0; dt < 4; ++dt) {
            const int d0 = dt * 16;
            f32x4 qT = (f32x4)0.0f, kT = (f32x4)0.0f, vn = (f32x4)0.0f;
#pragma unroll
            for (int kt = 0; kt < 2; ++kt) {
                const int woff = (h2 * 64 + d0 + c) * 64 + kt * 32 + 8 * g;
                const bf16x8 wq = *(const bf16x8*)&WqT[woff];
                const bf16x8 wk = *(const bf16x8*)&WkT[woff];
                const bf16x8 wv = *(const bf16x8*)&WvT[woff];
                qT = MFMA(wq, xA[kt], qT);   // D: Q[mt+c][d0+4g+r]
                kT = MFMA(wk, xA[kt], kT);   // D: K[mt+c][d0+4g+r]
                vn = MFMA(xA[kt], wv, vn);   // D: V[mt+4g+r][d0+c]
            }
            const float4 bqv = *(const float4*)&bq[h2 * 64 + d0 + 4 * g];
            const float4 bkv = *(const float4*)&bk[h2 * 64 + d0 + 4 * g];
            const float  bvv = bv[h2 * 64 + d0 + c];
            qout[dt] = pk4(qT[0] + bqv.x, qT[1] + bqv.y, qT[2] + bqv.z, qT[3] + bqv.w);
            uint2 kp, vp;
            kp.x = pk2(kT[0] + bkv.x, kT[1] + bkv.y);
            kp.y = pk2(kT[2] + bkv.z, kT[3] + bkv.w);
            vp.x = pk2(vn[0] + bvv, vn[1] + bvv);
            vp.y = pk2(vn[2] + bvv, vn[3] + bvv);
            *(uint2*)&KBn[sw64(mt + c, d0 + 4 * g)] = kp;
            *(uint2*)&VTn[sw128(d0 + c, mt + 4 * g)] = vp;
        }
    };

    // ---- prologue: head 0 into buffer 0 ----
    PROJ(0, sm, qcur);
    __syncthreads();

#pragma unroll 1
    for (int h = 0; h < NH; ++h) {
        ushort_t* bufc = sm + (h & 1) * 16384;
        ushort_t* bufn = sm + ((h & 1) ^ 1) * 16384;
        ushort_t* KBc  = bufc;
        ushort_t* VTc  = bufc + 8192;

        // pipeline: project next head (global weight loads hide under attention)
        if (h < NH - 1) PROJ(h + 1, bufn, qnext);

        const float eb0 = ebias[0 * NH + h], eb1 = ebias[1 * NH + h], eb2 = ebias[2 * NH + h];
        const float eb3 = ebias[3 * NH + h], eb4 = ebias[4 * NH + h];

        // ---- S^T tiles: lane (c,g) gets S[mt+c][16nt+4g+r] ----
        f32x4 s[8];
#pragma unroll
        for (int nt = 0; nt < 8; ++nt) {
            const int n0 = nt * 16;
            f32x4 acc = (f32x4)0.0f;
#pragma unroll
            for (int kt = 0; kt < 4; ++kt) {
                const bf16x4 kgr = *(const bf16x4*)&KBc[sw64(n0 + c, kt * 16 + 4 * g)];
                acc = MFMA16(kgr, qcur[kt], acc);
            }
#pragma unroll
            for (int r = 0; r < 4; ++r) {
                const int e = (epack[nt] >> (8 * r)) & 0xff;
                const float bias = (e == 1) ? eb1 : (e == 2) ? eb2 : (e == 3) ? eb3 : (e == 4) ? eb4 : eb0;
                float sv = acc[r] * 0.125f + bias;
                sv = (sv > 0.f) ? sv : 0.2f * sv;      // leaky BEFORE mask (ref order)
                acc[r] = (e > 0) ? sv : -1e9f;
            }
            s[nt] = acc;
        }

        // ---- softmax over the lane's own row: in-reg tree + 2 shuffles ----
        float mx;
        {
            f32x4 t0 = vmax4(s[0], s[1]), t1 = vmax4(s[2], s[3]);
            f32x4 t2 = vmax4(s[4], s[5]), t3 = vmax4(s[6], s[7]);
            t0 = vmax4(t0, t1); t2 = vmax4(t2, t3); t0 = vmax4(t0, t2);
            mx = fmaxf(fmaxf(t0[0], t0[1]), fmaxf(t0[2], t0[3]));
            mx = fmaxf(mx, __shfl_xor(mx, 16));
            mx = fmaxf(mx, __shfl_xor(mx, 32));
        }
#pragma unroll
        for (int nt = 0; nt < 8; ++nt)
#pragma unroll
            for (int r = 0; r < 4; ++r) s[nt][r] = __expf(s[nt][r] - mx);
        float sum;
        {
            f32x4 t0 = s[0] + s[1], t1 = s[2] + s[3], t2 = s[4] + s[5], t3 = s[6] + s[7];
            t0 = t0 + t1; t2 = t2 + t3; t0 = t0 + t2;
            sum = (t0[0] + t0[1]) + (t0[2] + t0[3]);
            sum += __shfl_xor(sum, 16);
            sum += __shfl_xor(sum, 32);
        }
        const float inv = 1.f / sum;

        // ---- P granules (registers only) ----
        bf16x4 pg[8];
#pragma unroll
        for (int nt = 0; nt < 8; ++nt)
            pg[nt] = pk4(s[nt][0] * inv, s[nt][1] * inv, s[nt][2] * inv, s[nt][3] * inv);

        // ---- O = P·V via mfma16: lane gets O[mt+c][d0+4g+r] ----
        f32x4 ot[4];
#pragma unroll
        for (int dt = 0; dt < 4; ++dt) ot[dt] = (f32x4)0.0f;
#pragma unroll
        for (int dt = 0; dt < 4; ++dt) {
            const int d0 = dt * 16;
#pragma unroll
            for (int nt = 0; nt < 8; ++nt) {
                const bf16x4 vgr = *(const bf16x4*)&VTc[sw128(d0 + c, nt * 16 + 4 * g)];
                ot[dt] = MFMA16(vgr, pg[nt], ot[dt]);
            }
        }

        // ---- out-proj accumulate straight from O granules ----
        bf16x4 ogr[4];
#pragma unroll
        for (int dt = 0; dt < 4; ++dt)
            ogr[dt] = pk4(ot[dt][0], ot[dt][1], ot[dt][2], ot[dt][3]);
#pragma unroll
        for (int nt4 = 0; nt4 < 4; ++nt4) {
            const int n0 = nt4 * 16;
#pragma unroll
            for (int dt = 0; dt < 4; ++dt) {
                const bf16x4 wgr = *(const bf16x4*)&WpT[(n0 + c) * 512 + h * 64 + dt * 16 + 4 * g];
                projacc[nt4] = MFMA16(ogr[dt], wgr, projacc[nt4]);
            }
        }

        __syncthreads();   // one barrier per head: bufn ready, bufc free
        if (h < NH - 1) {
#pragma unroll
            for (int dt = 0; dt < 4; ++dt) qcur[dt] = qnext[dt];
        }
    }

    // ---- epilogue: + bp, coalesced f32 stores ----
    {
        float* og = out + (size_t)b * NM * ND;
#pragma unroll
        for (int nt4 = 0; nt4 < 4; ++nt4) {
            const int n0 = nt4 * 16;
            const float bpv = bp[n0 + c];
#pragma unroll
            for (int r = 0; r < 4; ++r)
                og[(mt + 4 * g + r) * ND + n0 + c] = projacc[nt4][r] + bpv;
        }
    }
}

extern "C" void kernel_launch(void* const* d_in, const int* in_sizes, int n_in,
                              void* d_out, int out_size, void* d_ws, size_t ws_size,
                              hipStream_t stream) {
    const float* x     = (const float*)d_in[0];
    const int*   edges = (const int*)d_in[1];
    const float* Wq    = (const float*)d_in[2];
    const float* bq    = (const float*)d_in[3];
    const float* Wk    = (const float*)d_in[4];
    const float* bk    = (const float*)d_in[5];
    const float* Wv    = (const float*)d_in[6];
    const float* bv    = (const float*)d_in[7];
    const float* eb    = (const float*)d_in[8];
    const float* Wp    = (const float*)d_in[9];
    const float* bp    = (const float*)d_in[10];
    float* out = (float*)d_out;
    ushort_t* ws = (ushort_t*)d_ws;   // needs 262144 B

    hipLaunchKernelGGL(geat_prep, dim3(512), dim3(256), 0, stream, Wq, Wk, Wv, Wp, ws);
    hipLaunchKernelGGL(geat_pipe, dim3(NB), dim3(512), 0, stream,
                       x, edges, bq, bk, bv, eb, bp, ws, out);
}